// Round 7
// baseline (1053.608 us; speedup 1.0000x reference)
//
#include <hip/hip_runtime.h>

#define IN_F 128
#define OUT_F 128
#define BNODES 128          // nodes per aggregation bucket (64KB LDS f32 acc)

typedef unsigned int uint32;
typedef unsigned short ushort16;
using short8 = __attribute__((ext_vector_type(8))) short;   // 8 bf16 (4 VGPR)
using f32x4  = __attribute__((ext_vector_type(4))) float;   // MFMA acc

// f32 -> bf16 (round-to-nearest-even), raw u16 in low bits.
__device__ __forceinline__ uint32 f2bf(float f) {
    const uint32 u = __float_as_uint(f);
    return (u + 0x7FFFu + ((u >> 16) & 1u)) >> 16;
}
__device__ __forceinline__ uint32 pack_bf2(float lo, float hi) {
    return f2bf(lo) | (f2bf(hi) << 16);
}

// ---------------------------------------------------------------------------
// 0) Convert x and W to bf16.
// ---------------------------------------------------------------------------
__global__ __launch_bounds__(256) void k_cvt(
    const float* __restrict__ x, const float* __restrict__ W,
    uint32* __restrict__ xb, uint32* __restrict__ wb, int nx4, int nw4)
{
    const int i4 = blockIdx.x * 256 + threadIdx.x;
    if (i4 < nx4) {
        const float4 v = reinterpret_cast<const float4*>(x)[i4];
        uint2 st;
        st.x = pack_bf2(v.x, v.y);
        st.y = pack_bf2(v.z, v.w);
        reinterpret_cast<uint2*>(xb)[i4] = st;
    } else if (i4 - nx4 < nw4) {
        const int j4 = i4 - nx4;
        const float4 v = reinterpret_cast<const float4*>(W)[j4];
        uint2 st;
        st.x = pack_bf2(v.x, v.y);
        st.y = pack_bf2(v.z, v.w);
        reinterpret_cast<uint2*>(wb)[j4] = st;
    }
}

// ---------------------------------------------------------------------------
// 1) Per-node in-degree histogram (int atomics over 200KB -> cache-resident).
// ---------------------------------------------------------------------------
__global__ __launch_bounds__(256) void k_hist(
    const int* __restrict__ ei, int* __restrict__ deg_i, int nEdges)
{
    int e = blockIdx.x * blockDim.x + threadIdx.x;
    if (e < nEdges) {
        atomicAdd(&deg_i[ei[nEdges + e]], 1);
    }
}

// ---------------------------------------------------------------------------
// 2) Bucket-level scan: bucket b covers nodes [b*128, b*128+128).
//    count[b] = sum deg_i over bucket; exclusive-scan -> boff, cursor copy.
//    One block, 512 threads (nb = 391 <= 512).
// ---------------------------------------------------------------------------
__global__ __launch_bounds__(512) void k_bscan(
    const int* __restrict__ deg_i, int* __restrict__ boff,
    int* __restrict__ bcur, int n, int nb)
{
    __shared__ int sh[512];
    const int t = threadIdx.x;

    int s = 0;
    if (t < nb) {
        const int base = t * BNODES;
        const int lim = (base + BNODES < n) ? base + BNODES : n;
        if (lim - base == BNODES) {
            const int4* p = reinterpret_cast<const int4*>(deg_i + base);
#pragma unroll
            for (int i = 0; i < BNODES / 4; ++i) {
                const int4 v = p[i];
                s += v.x + v.y + v.z + v.w;
            }
        } else {
            for (int i = base; i < lim; ++i) s += deg_i[i];
        }
    }
    sh[t] = s;
    __syncthreads();
    for (int ofs = 1; ofs < 512; ofs <<= 1) {
        int u = (t >= ofs) ? sh[t - ofs] : 0;
        __syncthreads();
        sh[t] += u;
        __syncthreads();
    }
    if (t < nb) {
        const int ex = sh[t] - s;       // exclusive
        boff[t] = ex;
        bcur[t] = ex;
        if (t == nb - 1) boff[nb] = sh[t];
    }
}

// ---------------------------------------------------------------------------
// 3) Bin edges by bucket: ebuf[pos] = (dst&127)<<16 | src.
//    Appends within a bucket are sequential -> no write amplification.
//    (Requires nNodes <= 65536 for the 16-bit src pack: here N=50000.)
// ---------------------------------------------------------------------------
__global__ __launch_bounds__(256) void k_bin(
    const int* __restrict__ ei, int* __restrict__ bcur,
    uint32* __restrict__ ebuf, int nEdges)
{
    const int e0 = (blockIdx.x * 256 + threadIdx.x) * 4;
    if (e0 + 4 <= nEdges) {
        const int4 src4 = *reinterpret_cast<const int4*>(ei + e0);
        const int4 dst4 = *reinterpret_cast<const int4*>(ei + nEdges + e0);
        int pos;
        pos = atomicAdd(&bcur[dst4.x >> 7], 1);
        ebuf[pos] = ((uint32)(dst4.x & (BNODES - 1)) << 16) | (uint32)src4.x;
        pos = atomicAdd(&bcur[dst4.y >> 7], 1);
        ebuf[pos] = ((uint32)(dst4.y & (BNODES - 1)) << 16) | (uint32)src4.y;
        pos = atomicAdd(&bcur[dst4.z >> 7], 1);
        ebuf[pos] = ((uint32)(dst4.z & (BNODES - 1)) << 16) | (uint32)src4.z;
        pos = atomicAdd(&bcur[dst4.w >> 7], 1);
        ebuf[pos] = ((uint32)(dst4.w & (BNODES - 1)) << 16) | (uint32)src4.w;
    } else {
        for (int e = e0; e < nEdges; ++e) {
            const int src = ei[e];
            const int dst = ei[nEdges + e];
            const int pos = atomicAdd(&bcur[dst >> 7], 1);
            ebuf[pos] = ((uint32)(dst & (BNODES - 1)) << 16) | (uint32)src;
        }
    }
}

// ---------------------------------------------------------------------------
// 4) Bucket aggregation: block b accumulates its 128 nodes in LDS f32,
//    wave per edge: coalesced 256B x-row read + 2 LDS f32 atomic adds/lane.
//    Columns XOR-swizzled by (node&3)<<3 so the epilogue's row-major reads
//    don't all land in one bank (row stride 128 dwords == 0 mod 32).
//    Epilogue: divide by deg, pack bf16, write h.
// ---------------------------------------------------------------------------
__global__ __launch_bounds__(512) void k_agg(
    const uint32* __restrict__ xb2,    // [N][64] bf16x2
    const uint32* __restrict__ ebuf,
    const int* __restrict__ boff,
    const int* __restrict__ deg_i,
    uint32* __restrict__ hb2,          // [N][64] bf16x2
    int nNodes)
{
    __shared__ float acc[BNODES][IN_F];     // 64KB

    const int t = threadIdx.x;
    const int b = blockIdx.x;

    // zero LDS: 512 threads x 8 float4
    float4 z = {0.f, 0.f, 0.f, 0.f};
#pragma unroll
    for (int i = 0; i < 8; ++i)
        reinterpret_cast<float4*>(&acc[0][0])[i * 512 + t] = z;
    __syncthreads();

    const int s  = boff[b];
    const int e1 = boff[b + 1];
    const int wave = t >> 6;
    const int lane = t & 63;

    for (int i = s + wave; i < e1; i += 8) {
        const uint32 e = ebuf[i];               // wave-uniform
        const uint32 src = e & 0xFFFFu;
        const int    ld  = (int)(e >> 16);
        const uint32 u = xb2[(size_t)src * 64 + lane];
        const int col = (2 * lane) ^ ((ld & 3) << 3);   // swizzled, bijective
        atomicAdd(&acc[ld][col],     __uint_as_float(u << 16));
        atomicAdd(&acc[ld][col + 1], __uint_as_float(u & 0xFFFF0000u));
    }
    __syncthreads();

    // epilogue: thread t -> node t>>2, feature block (t&3)*32
    const int nd = t >> 2;
    const int node = b * BNODES + nd;
    if (node < nNodes) {
        const int d = deg_i[node];
        const float inv = 1.0f / (float)(d > 0 ? d : 1);
        const int f0 = (t & 3) * 32;
        const int swz = (nd & 3) << 3;          // flips 32B blocks: f4-safe
#pragma unroll
        for (int q = 0; q < 4; ++q) {
            const int fb = (f0 + q * 8) ^ swz;
            const float4 a  = *reinterpret_cast<const float4*>(&acc[nd][fb]);
            const float4 b4 = *reinterpret_cast<const float4*>(&acc[nd][fb + 4]);
            uint4 st;
            st.x = pack_bf2(a.x * inv,  a.y * inv);
            st.y = pack_bf2(a.z * inv,  a.w * inv);
            st.z = pack_bf2(b4.x * inv, b4.y * inv);
            st.w = pack_bf2(b4.z * inv, b4.w * inv);
            reinterpret_cast<uint4*>(hb2 + (size_t)node * 64)[(f0 >> 3) + q] = st;
        }
    }
}

// ---------------------------------------------------------------------------
// 5) out = h @ W.T + b via mfma_f32_16x16x32_bf16 (m89-verified C/D layout).
// ---------------------------------------------------------------------------
__global__ __launch_bounds__(256) void k_mm(
    const ushort16* __restrict__ hbf,   // [M][128] bf16
    const ushort16* __restrict__ wbf,   // [128][128] bf16 (row=out_f, col=in_f)
    const float* __restrict__ bias,
    float* __restrict__ out, int nNodes)
{
    const int wave = threadIdx.x >> 6;
    const int lane = threadIdx.x & 63;
    const int m0 = blockIdx.x * 128 + wave * 32;   // 32 rows per wave
    const int lrow = lane & 15;
    const int kgrp = lane >> 4;

    short8 a[2][4];
#pragma unroll
    for (int mt = 0; mt < 2; ++mt) {
        int mrow = m0 + mt * 16 + lrow;
        if (mrow >= nNodes) mrow = nNodes - 1;          // clamp (tail safety)
        const ushort16* hrow = hbf + (size_t)mrow * IN_F;
#pragma unroll
        for (int kt = 0; kt < 4; ++kt) {
            a[mt][kt] = *reinterpret_cast<const short8*>(hrow + kt * 32 + kgrp * 8);
        }
    }

#pragma unroll
    for (int nt = 0; nt < 8; ++nt) {
        const int n0 = nt * 16;
        const ushort16* wrow = wbf + (size_t)(n0 + lrow) * IN_F;
        const float bv = bias[n0 + lrow];

        f32x4 acc0 = {bv, bv, bv, bv};
        f32x4 acc1 = {bv, bv, bv, bv};
#pragma unroll
        for (int kt = 0; kt < 4; ++kt) {
            const short8 b = *reinterpret_cast<const short8*>(wrow + kt * 32 + kgrp * 8);
            acc0 = __builtin_amdgcn_mfma_f32_16x16x32_bf16(a[0][kt], b, acc0, 0, 0, 0);
            acc1 = __builtin_amdgcn_mfma_f32_16x16x32_bf16(a[1][kt], b, acc1, 0, 0, 0);
        }
#pragma unroll
        for (int r = 0; r < 4; ++r) {
            const int row0 = m0 + kgrp * 4 + r;
            const int row1 = m0 + 16 + kgrp * 4 + r;
            if (row0 < nNodes) out[(size_t)row0 * OUT_F + n0 + lrow] = acc0[r];
            if (row1 < nNodes) out[(size_t)row1 * OUT_F + n0 + lrow] = acc1[r];
        }
    }
}

extern "C" void kernel_launch(void* const* d_in, const int* in_sizes, int n_in,
                              void* d_out, int out_size, void* d_ws, size_t ws_size,
                              hipStream_t stream)
{
    const float* x   = (const float*)d_in[0];
    const int*   ei  = (const int*)d_in[1];
    const float* W   = (const float*)d_in[3];
    const float* b   = (const float*)d_in[4];
    float*       out = (float*)d_out;

    const int nNodes = in_sizes[0] / IN_F;            // 50000
    const int nEdges = in_sizes[1] / 2;               // 800000
    const int nb = (nNodes + BNODES - 1) / BNODES;    // 391 buckets

    // ws layout (ints): deg_i[n] boff[nb+1] bcur[nb] ebuf[E]
    //                   | hbf[n*128 bf16] wbf[16384 bf16]
    int*    deg_i = (int*)d_ws;
    int*    boff  = deg_i + nNodes;
    int*    bcur  = boff + (nb + 1);
    uint32* ebuf  = (uint32*)(bcur + nb);
    ushort16* hbf = (ushort16*)(ebuf + nEdges);
    ushort16* wbf = hbf + (size_t)nNodes * IN_F;

    // x_bf16 lives in d_out's first 12.8MB: dead before k_mm writes out.
    uint32* xb = (uint32*)d_out;

    (void)hipMemsetAsync(deg_i, 0, (size_t)nNodes * sizeof(int), stream);

    const int nx4 = (nNodes * IN_F) / 4;
    const int nw4 = (OUT_F * IN_F) / 4;
    k_cvt<<<(nx4 + nw4 + 255) / 256, 256, 0, stream>>>(x, W, xb, (uint32*)wbf,
                                                       nx4, nw4);

    const int eb = (nEdges + 255) / 256;
    k_hist<<<eb, 256, 0, stream>>>(ei, deg_i, nEdges);

    k_bscan<<<1, 512, 0, stream>>>(deg_i, boff, bcur, nNodes, nb);

    const int bb = (nEdges / 4 + 255) / 256;
    k_bin<<<bb, 256, 0, stream>>>(ei, bcur, ebuf, nEdges);

    k_agg<<<nb, 512, 0, stream>>>(xb, ebuf, boff, deg_i, (uint32*)hbf, nNodes);

    const int mb = (nNodes + 127) / 128;   // 391 blocks
    k_mm<<<mb, 256, 0, stream>>>(hbf, wbf, b, out, nNodes);
}

// Round 8
// 398.262 us; speedup vs baseline: 2.6455x; 2.6455x over previous
//
#include <hip/hip_runtime.h>

#define IN_F 128
#define OUT_F 128
#define BNODES 128          // nodes per bucket (bucket = 1 k_sort block)

typedef unsigned int uint32;
typedef unsigned short ushort16;
using short8 = __attribute__((ext_vector_type(8))) short;   // 8 bf16 (4 VGPR)
using f32x4  = __attribute__((ext_vector_type(4))) float;   // MFMA acc

// f32 -> bf16 (round-to-nearest-even), raw u16 in low bits.
__device__ __forceinline__ uint32 f2bf(float f) {
    const uint32 u = __float_as_uint(f);
    return (u + 0x7FFFu + ((u >> 16) & 1u)) >> 16;
}
__device__ __forceinline__ uint32 pack_bf2(float lo, float hi) {
    return f2bf(lo) | (f2bf(hi) << 16);
}

// ---------------------------------------------------------------------------
// 0) Convert x and W to bf16.
// ---------------------------------------------------------------------------
__global__ __launch_bounds__(256) void k_cvt(
    const float* __restrict__ x, const float* __restrict__ W,
    uint32* __restrict__ xb, uint32* __restrict__ wb, int nx4, int nw4)
{
    const int i4 = blockIdx.x * 256 + threadIdx.x;
    if (i4 < nx4) {
        const float4 v = reinterpret_cast<const float4*>(x)[i4];
        uint2 st;
        st.x = pack_bf2(v.x, v.y);
        st.y = pack_bf2(v.z, v.w);
        reinterpret_cast<uint2*>(xb)[i4] = st;
    } else if (i4 - nx4 < nw4) {
        const int j4 = i4 - nx4;
        const float4 v = reinterpret_cast<const float4*>(W)[j4];
        uint2 st;
        st.x = pack_bf2(v.x, v.y);
        st.y = pack_bf2(v.z, v.w);
        reinterpret_cast<uint2*>(wb)[j4] = st;
    }
}

// ---------------------------------------------------------------------------
// 1) Per-node in-degree histogram (int atomics over 200KB -> cache-resident).
// ---------------------------------------------------------------------------
__global__ __launch_bounds__(256) void k_hist(
    const int* __restrict__ ei, int* __restrict__ deg_i, int nEdges)
{
    int e = blockIdx.x * blockDim.x + threadIdx.x;
    if (e < nEdges) {
        atomicAdd(&deg_i[ei[nEdges + e]], 1);
    }
}

// ---------------------------------------------------------------------------
// 2) Three-phase parallel exclusive scan of deg_i[n] -> off[n];
//    scan_c also emits the bucket append-cursors bcurB[b] = off[b*128].
// ---------------------------------------------------------------------------
__global__ __launch_bounds__(256) void k_scan_a(
    const int* __restrict__ deg_i, int* __restrict__ escan,
    int* __restrict__ bsum, int n)
{
    __shared__ int sh[256];
    const int t = threadIdx.x;
    const int i = blockIdx.x * 256 + t;
    int v = (i < n) ? deg_i[i] : 0;
    sh[t] = v;
    __syncthreads();
    for (int ofs = 1; ofs < 256; ofs <<= 1) {
        int u = (t >= ofs) ? sh[t - ofs] : 0;
        __syncthreads();
        sh[t] += u;
        __syncthreads();
    }
    if (i < n) escan[i] = sh[t] - v;            // exclusive
    if (t == 255) bsum[blockIdx.x] = sh[255];
}

__global__ __launch_bounds__(256) void k_scan_b(
    const int* __restrict__ bsum, int* __restrict__ bbase, int nb)
{
    __shared__ int sh[256];
    const int t = threadIdx.x;
    int v = (t < nb) ? bsum[t] : 0;
    sh[t] = v;
    __syncthreads();
    for (int ofs = 1; ofs < 256; ofs <<= 1) {
        int u = (t >= ofs) ? sh[t - ofs] : 0;
        __syncthreads();
        sh[t] += u;
        __syncthreads();
    }
    if (t < nb) bbase[t] = sh[t] - v;           // exclusive
}

__global__ __launch_bounds__(256) void k_scan_c(
    const int* __restrict__ escan, const int* __restrict__ bbase,
    int* __restrict__ off, int* __restrict__ bcurB, int n)
{
    const int i = blockIdx.x * 256 + threadIdx.x;
    if (i < n) {
        const int o = escan[i] + bbase[blockIdx.x];
        off[i] = o;
        if ((i & (BNODES - 1)) == 0) bcurB[i >> 7] = o;   // bucket cursor
    }
}

// ---------------------------------------------------------------------------
// 3) Bin edges by 128-node bucket: ebuf[pos] = (dst&127)<<16 | src.
//    Appends within a bucket are sequential -> writes fill 64B lines.
//    (Requires nNodes <= 65536 for the 16-bit src pack: here N=50000.)
// ---------------------------------------------------------------------------
__global__ __launch_bounds__(256) void k_bin(
    const int* __restrict__ ei, int* __restrict__ bcurB,
    uint32* __restrict__ ebuf, int nEdges)
{
    const int e0 = (blockIdx.x * 256 + threadIdx.x) * 4;
    if (e0 + 4 <= nEdges) {
        const int4 src4 = *reinterpret_cast<const int4*>(ei + e0);
        const int4 dst4 = *reinterpret_cast<const int4*>(ei + nEdges + e0);
        int pos;
        pos = atomicAdd(&bcurB[dst4.x >> 7], 1);
        ebuf[pos] = ((uint32)(dst4.x & (BNODES - 1)) << 16) | (uint32)src4.x;
        pos = atomicAdd(&bcurB[dst4.y >> 7], 1);
        ebuf[pos] = ((uint32)(dst4.y & (BNODES - 1)) << 16) | (uint32)src4.y;
        pos = atomicAdd(&bcurB[dst4.z >> 7], 1);
        ebuf[pos] = ((uint32)(dst4.z & (BNODES - 1)) << 16) | (uint32)src4.z;
        pos = atomicAdd(&bcurB[dst4.w >> 7], 1);
        ebuf[pos] = ((uint32)(dst4.w & (BNODES - 1)) << 16) | (uint32)src4.w;
    } else {
        for (int e = e0; e < nEdges; ++e) {
            const int src = ei[e];
            const int dst = ei[nEdges + e];
            const int pos = atomicAdd(&bcurB[dst >> 7], 1);
            ebuf[pos] = ((uint32)(dst & (BNODES - 1)) << 16) | (uint32)src;
        }
    }
}

// ---------------------------------------------------------------------------
// 4) Per-bucket ordering pass: block b streams its ebuf segment and places
//    each src at perm[off[dst] + rank] using 128 LDS int cursors.
//    All perm writes land in the bucket's contiguous ~8KB CSR window.
// ---------------------------------------------------------------------------
__global__ __launch_bounds__(256) void k_sort(
    const uint32* __restrict__ ebuf, const int* __restrict__ off,
    int* __restrict__ perm, int nNodes, int nEdges, int nb)
{
    __shared__ int cur[BNODES];
    const int b = blockIdx.x;
    const int t = threadIdx.x;

    const int node0 = b * BNODES;
    if (t < BNODES) {
        const int node = node0 + t;
        cur[t] = (node < nNodes) ? off[node] : 0;
    }
    __syncthreads();

    const int s = off[node0];
    const int e = (b == nb - 1) ? nEdges : off[node0 + BNODES];

    for (int i = s + t; i < e; i += 256) {
        const uint32 u = ebuf[i];
        const int ld  = (int)(u >> 16);
        const int src = (int)(u & 0xFFFFu);
        const int pos = atomicAdd(&cur[ld], 1);
        perm[pos] = src;
    }
}

// ---------------------------------------------------------------------------
// 5) Gather-side reduction over bf16 x: one wave per node, lane holds 2
//    features (bf16x2 dword). f32 accumulation, bf16 output row.
// ---------------------------------------------------------------------------
__global__ __launch_bounds__(256) void k_gather(
    const uint32* __restrict__ xb2,    // [N][64] bf16x2
    const int* __restrict__ perm,
    const int* __restrict__ off,
    const int* __restrict__ deg_i,
    uint32* __restrict__ hb2,          // [N][64] bf16x2
    int nNodes)
{
    const int node = (blockIdx.x << 2) + (threadIdx.x >> 6);
    const int lane = threadIdx.x & 63;
    if (node >= nNodes) return;

    const int s = off[node];
    const int d = deg_i[node];

    float ax = 0.0f, ay = 0.0f;
    int i = 0;
    for (; i + 4 <= d; i += 4) {
        const uint32 u0 = xb2[(size_t)perm[s + i + 0] * 64 + lane];
        const uint32 u1 = xb2[(size_t)perm[s + i + 1] * 64 + lane];
        const uint32 u2 = xb2[(size_t)perm[s + i + 2] * 64 + lane];
        const uint32 u3 = xb2[(size_t)perm[s + i + 3] * 64 + lane];
        ax += __uint_as_float(u0 << 16);
        ay += __uint_as_float(u0 & 0xFFFF0000u);
        ax += __uint_as_float(u1 << 16);
        ay += __uint_as_float(u1 & 0xFFFF0000u);
        ax += __uint_as_float(u2 << 16);
        ay += __uint_as_float(u2 & 0xFFFF0000u);
        ax += __uint_as_float(u3 << 16);
        ay += __uint_as_float(u3 & 0xFFFF0000u);
    }
    for (; i < d; ++i) {
        const uint32 u = xb2[(size_t)perm[s + i] * 64 + lane];
        ax += __uint_as_float(u << 16);
        ay += __uint_as_float(u & 0xFFFF0000u);
    }

    const float inv = 1.0f / (float)(d > 0 ? d : 1);
    hb2[(size_t)node * 64 + lane] = pack_bf2(ax * inv, ay * inv);
}

// ---------------------------------------------------------------------------
// 6) out = h @ W.T + b via mfma_f32_16x16x32_bf16 (m89-verified C/D layout).
// ---------------------------------------------------------------------------
__global__ __launch_bounds__(256) void k_mm(
    const ushort16* __restrict__ hbf,   // [M][128] bf16
    const ushort16* __restrict__ wbf,   // [128][128] bf16 (row=out_f, col=in_f)
    const float* __restrict__ bias,
    float* __restrict__ out, int nNodes)
{
    const int wave = threadIdx.x >> 6;
    const int lane = threadIdx.x & 63;
    const int m0 = blockIdx.x * 128 + wave * 32;   // 32 rows per wave
    const int lrow = lane & 15;
    const int kgrp = lane >> 4;

    short8 a[2][4];
#pragma unroll
    for (int mt = 0; mt < 2; ++mt) {
        int mrow = m0 + mt * 16 + lrow;
        if (mrow >= nNodes) mrow = nNodes - 1;          // clamp (tail safety)
        const ushort16* hrow = hbf + (size_t)mrow * IN_F;
#pragma unroll
        for (int kt = 0; kt < 4; ++kt) {
            a[mt][kt] = *reinterpret_cast<const short8*>(hrow + kt * 32 + kgrp * 8);
        }
    }

#pragma unroll
    for (int nt = 0; nt < 8; ++nt) {
        const int n0 = nt * 16;
        const ushort16* wrow = wbf + (size_t)(n0 + lrow) * IN_F;
        const float bv = bias[n0 + lrow];

        f32x4 acc0 = {bv, bv, bv, bv};
        f32x4 acc1 = {bv, bv, bv, bv};
#pragma unroll
        for (int kt = 0; kt < 4; ++kt) {
            const short8 b = *reinterpret_cast<const short8*>(wrow + kt * 32 + kgrp * 8);
            acc0 = __builtin_amdgcn_mfma_f32_16x16x32_bf16(a[0][kt], b, acc0, 0, 0, 0);
            acc1 = __builtin_amdgcn_mfma_f32_16x16x32_bf16(a[1][kt], b, acc1, 0, 0, 0);
        }
#pragma unroll
        for (int r = 0; r < 4; ++r) {
            const int row0 = m0 + kgrp * 4 + r;
            const int row1 = m0 + 16 + kgrp * 4 + r;
            if (row0 < nNodes) out[(size_t)row0 * OUT_F + n0 + lrow] = acc0[r];
            if (row1 < nNodes) out[(size_t)row1 * OUT_F + n0 + lrow] = acc1[r];
        }
    }
}

extern "C" void kernel_launch(void* const* d_in, const int* in_sizes, int n_in,
                              void* d_out, int out_size, void* d_ws, size_t ws_size,
                              hipStream_t stream)
{
    const float* x   = (const float*)d_in[0];
    const int*   ei  = (const int*)d_in[1];
    const float* W   = (const float*)d_in[3];
    const float* b   = (const float*)d_in[4];
    float*       out = (float*)d_out;

    const int nNodes = in_sizes[0] / IN_F;            // 50000
    const int nEdges = in_sizes[1] / 2;               // 800000
    const int nb  = (nNodes + BNODES - 1) / BNODES;   // 391 buckets
    const int nsb = (nNodes + 255) / 256;             // 196 scan blocks

    // ws layout (ints): deg_i[n] off[n] escan[n] bsum[nsb] bbase[nsb]
    //                   bcurB[nb] ebuf[E] perm[E] | hbf[n*128 bf16] wbf[16K bf16]
    int*    deg_i = (int*)d_ws;
    int*    off   = deg_i + nNodes;
    int*    escan = off + nNodes;
    int*    bsum  = escan + nNodes;
    int*    bbase = bsum + nsb;
    int*    bcurB = bbase + nsb;
    uint32* ebuf  = (uint32*)(bcurB + nb);
    int*    perm  = (int*)(ebuf + nEdges);
    ushort16* hbf = (ushort16*)(perm + nEdges);
    ushort16* wbf = hbf + (size_t)nNodes * IN_F;

    // x_bf16 lives in d_out's first 12.8MB: dead before k_mm writes out.
    uint32* xb = (uint32*)d_out;

    (void)hipMemsetAsync(deg_i, 0, (size_t)nNodes * sizeof(int), stream);

    const int nx4 = (nNodes * IN_F) / 4;
    const int nw4 = (OUT_F * IN_F) / 4;
    k_cvt<<<(nx4 + nw4 + 255) / 256, 256, 0, stream>>>(x, W, xb, (uint32*)wbf,
                                                       nx4, nw4);

    const int eb = (nEdges + 255) / 256;
    k_hist<<<eb, 256, 0, stream>>>(ei, deg_i, nEdges);

    k_scan_a<<<nsb, 256, 0, stream>>>(deg_i, escan, bsum, nNodes);
    k_scan_b<<<1, 256, 0, stream>>>(bsum, bbase, nsb);
    k_scan_c<<<nsb, 256, 0, stream>>>(escan, bbase, off, bcurB, nNodes);

    const int bb = (nEdges / 4 + 255) / 256;
    k_bin<<<bb, 256, 0, stream>>>(ei, bcurB, ebuf, nEdges);

    k_sort<<<nb, 256, 0, stream>>>(ebuf, off, perm, nNodes, nEdges, nb);

    const int gb = (nNodes + 3) / 4;
    k_gather<<<gb, 256, 0, stream>>>(xb, perm, off, deg_i, (uint32*)hbf, nNodes);

    const int mb = (nNodes + 127) / 128;   // 391 blocks
    k_mm<<<mb, 256, 0, stream>>>(hbf, wbf, b, out, nNodes);
}

// Round 9
// 149.193 us; speedup vs baseline: 7.0620x; 2.6694x over previous
//
#include <hip/hip_runtime.h>

#define IN_F 128
#define OUT_F 128

typedef unsigned int uint32;
typedef unsigned short ushort16;
using short8 = __attribute__((ext_vector_type(8))) short;   // 8 bf16 (4 VGPR)
using f32x4  = __attribute__((ext_vector_type(4))) float;   // MFMA acc

// f32 -> bf16 (round-to-nearest-even), raw u16 in low bits.
__device__ __forceinline__ uint32 f2bf(float f) {
    const uint32 u = __float_as_uint(f);
    return (u + 0x7FFFu + ((u >> 16) & 1u)) >> 16;
}
__device__ __forceinline__ uint32 pack_bf2(float lo, float hi) {
    return f2bf(lo) | (f2bf(hi) << 16);
}

// ---------------------------------------------------------------------------
// 0) Convert x and W to bf16.
// ---------------------------------------------------------------------------
__global__ __launch_bounds__(256) void k_cvt(
    const float* __restrict__ x, const float* __restrict__ W,
    uint32* __restrict__ xb, uint32* __restrict__ wb, int nx4, int nw4)
{
    const int i4 = blockIdx.x * 256 + threadIdx.x;
    if (i4 < nx4) {
        const float4 v = reinterpret_cast<const float4*>(x)[i4];
        uint2 st;
        st.x = pack_bf2(v.x, v.y);
        st.y = pack_bf2(v.z, v.w);
        reinterpret_cast<uint2*>(xb)[i4] = st;
    } else if (i4 - nx4 < nw4) {
        const int j4 = i4 - nx4;
        const float4 v = reinterpret_cast<const float4*>(W)[j4];
        uint2 st;
        st.x = pack_bf2(v.x, v.y);
        st.y = pack_bf2(v.z, v.w);
        reinterpret_cast<uint2*>(wb)[j4] = st;
    }
}

// ---------------------------------------------------------------------------
// 1) Per-node in-degree histogram (int atomics over 200KB -> cache-resident).
// ---------------------------------------------------------------------------
__global__ __launch_bounds__(256) void k_hist(
    const int* __restrict__ ei, int* __restrict__ deg_i, int nEdges)
{
    int e = blockIdx.x * blockDim.x + threadIdx.x;
    if (e < nEdges) {
        atomicAdd(&deg_i[ei[nEdges + e]], 1);
    }
}

// ---------------------------------------------------------------------------
// 2) Three-phase parallel exclusive scan of deg_i[n] -> off[n] (+cursor copy).
// ---------------------------------------------------------------------------
__global__ __launch_bounds__(256) void k_scan_a(
    const int* __restrict__ deg_i, int* __restrict__ escan,
    int* __restrict__ bsum, int n)
{
    __shared__ int sh[256];
    const int t = threadIdx.x;
    const int i = blockIdx.x * 256 + t;
    int v = (i < n) ? deg_i[i] : 0;
    sh[t] = v;
    __syncthreads();
    for (int ofs = 1; ofs < 256; ofs <<= 1) {
        int u = (t >= ofs) ? sh[t - ofs] : 0;
        __syncthreads();
        sh[t] += u;
        __syncthreads();
    }
    if (i < n) escan[i] = sh[t] - v;            // exclusive
    if (t == 255) bsum[blockIdx.x] = sh[255];
}

__global__ __launch_bounds__(256) void k_scan_b(
    const int* __restrict__ bsum, int* __restrict__ bbase, int nb)
{
    __shared__ int sh[256];
    const int t = threadIdx.x;
    int v = (t < nb) ? bsum[t] : 0;
    sh[t] = v;
    __syncthreads();
    for (int ofs = 1; ofs < 256; ofs <<= 1) {
        int u = (t >= ofs) ? sh[t - ofs] : 0;
        __syncthreads();
        sh[t] += u;
        __syncthreads();
    }
    if (t < nb) bbase[t] = sh[t] - v;           // exclusive
}

__global__ __launch_bounds__(256) void k_scan_c(
    const int* __restrict__ escan, const int* __restrict__ bbase,
    int* __restrict__ off, int* __restrict__ cursor, int n)
{
    const int i = blockIdx.x * 256 + threadIdx.x;
    if (i < n) {
        const int o = escan[i] + bbase[blockIdx.x];
        off[i] = o;
        cursor[i] = o;
    }
}

// ---------------------------------------------------------------------------
// 3) CSR bucketing with XCD-class filtering to kill write amplification.
//    Grid = 8 x chunks. Block handles chunk blockIdx>>3, but only edges whose
//    destination bucket class ((dst>>7)&7) == blockIdx&7. Since blockIdx%8
//    maps round-robin to XCDs, each perm region is written by ONE XCD ->
//    its L2 lines fill completely before eviction (WRITE ~= payload).
//    Per-node cursors (50k) keep atomic contention low. Mapping assumption
//    affects speed only, never correctness.
// ---------------------------------------------------------------------------
__global__ __launch_bounds__(256) void k_scatter_ids(
    const int* __restrict__ ei, int* __restrict__ cursor,
    int* __restrict__ perm, int nEdges)
{
    const int cls = blockIdx.x & 7;
    const int e0 = ((blockIdx.x >> 3) * 256 + threadIdx.x) * 4;
    if (e0 >= nEdges) return;

    if (e0 + 4 <= nEdges) {
        const int4 dst4 = *reinterpret_cast<const int4*>(ei + nEdges + e0);
        const int4 src4 = *reinterpret_cast<const int4*>(ei + e0);
        if (((dst4.x >> 7) & 7) == cls) {
            const int p = atomicAdd(&cursor[dst4.x], 1);
            perm[p] = src4.x;
        }
        if (((dst4.y >> 7) & 7) == cls) {
            const int p = atomicAdd(&cursor[dst4.y], 1);
            perm[p] = src4.y;
        }
        if (((dst4.z >> 7) & 7) == cls) {
            const int p = atomicAdd(&cursor[dst4.z], 1);
            perm[p] = src4.z;
        }
        if (((dst4.w >> 7) & 7) == cls) {
            const int p = atomicAdd(&cursor[dst4.w], 1);
            perm[p] = src4.w;
        }
    } else {
        for (int e = e0; e < nEdges; ++e) {
            const int dst = ei[nEdges + e];
            if (((dst >> 7) & 7) == cls) {
                const int p = atomicAdd(&cursor[dst], 1);
                perm[p] = ei[e];
            }
        }
    }
}

// ---------------------------------------------------------------------------
// 4) Gather-side reduction over bf16 x: one wave per node, lane holds 2
//    features (bf16x2 dword). f32 accumulation, bf16 output row.
// ---------------------------------------------------------------------------
__global__ __launch_bounds__(256) void k_gather(
    const uint32* __restrict__ xb2,    // [N][64] bf16x2
    const int* __restrict__ perm,
    const int* __restrict__ off,
    const int* __restrict__ deg_i,
    uint32* __restrict__ hb2,          // [N][64] bf16x2
    int nNodes)
{
    const int node = (blockIdx.x << 2) + (threadIdx.x >> 6);
    const int lane = threadIdx.x & 63;
    if (node >= nNodes) return;

    const int s = off[node];
    const int d = deg_i[node];

    float ax = 0.0f, ay = 0.0f;
    int i = 0;
    for (; i + 4 <= d; i += 4) {
        const uint32 u0 = xb2[(size_t)perm[s + i + 0] * 64 + lane];
        const uint32 u1 = xb2[(size_t)perm[s + i + 1] * 64 + lane];
        const uint32 u2 = xb2[(size_t)perm[s + i + 2] * 64 + lane];
        const uint32 u3 = xb2[(size_t)perm[s + i + 3] * 64 + lane];
        ax += __uint_as_float(u0 << 16);
        ay += __uint_as_float(u0 & 0xFFFF0000u);
        ax += __uint_as_float(u1 << 16);
        ay += __uint_as_float(u1 & 0xFFFF0000u);
        ax += __uint_as_float(u2 << 16);
        ay += __uint_as_float(u2 & 0xFFFF0000u);
        ax += __uint_as_float(u3 << 16);
        ay += __uint_as_float(u3 & 0xFFFF0000u);
    }
    for (; i < d; ++i) {
        const uint32 u = xb2[(size_t)perm[s + i] * 64 + lane];
        ax += __uint_as_float(u << 16);
        ay += __uint_as_float(u & 0xFFFF0000u);
    }

    const float inv = 1.0f / (float)(d > 0 ? d : 1);
    hb2[(size_t)node * 64 + lane] = pack_bf2(ax * inv, ay * inv);
}

// ---------------------------------------------------------------------------
// 5) out = h @ W.T + b via mfma_f32_16x16x32_bf16 (m89-verified C/D layout).
// ---------------------------------------------------------------------------
__global__ __launch_bounds__(256) void k_mm(
    const ushort16* __restrict__ hbf,   // [M][128] bf16
    const ushort16* __restrict__ wbf,   // [128][128] bf16 (row=out_f, col=in_f)
    const float* __restrict__ bias,
    float* __restrict__ out, int nNodes)
{
    const int wave = threadIdx.x >> 6;
    const int lane = threadIdx.x & 63;
    const int m0 = blockIdx.x * 128 + wave * 32;   // 32 rows per wave
    const int lrow = lane & 15;
    const int kgrp = lane >> 4;

    short8 a[2][4];
#pragma unroll
    for (int mt = 0; mt < 2; ++mt) {
        int mrow = m0 + mt * 16 + lrow;
        if (mrow >= nNodes) mrow = nNodes - 1;          // clamp (tail safety)
        const ushort16* hrow = hbf + (size_t)mrow * IN_F;
#pragma unroll
        for (int kt = 0; kt < 4; ++kt) {
            a[mt][kt] = *reinterpret_cast<const short8*>(hrow + kt * 32 + kgrp * 8);
        }
    }

#pragma unroll
    for (int nt = 0; nt < 8; ++nt) {
        const int n0 = nt * 16;
        const ushort16* wrow = wbf + (size_t)(n0 + lrow) * IN_F;
        const float bv = bias[n0 + lrow];

        f32x4 acc0 = {bv, bv, bv, bv};
        f32x4 acc1 = {bv, bv, bv, bv};
#pragma unroll
        for (int kt = 0; kt < 4; ++kt) {
            const short8 b = *reinterpret_cast<const short8*>(wrow + kt * 32 + kgrp * 8);
            acc0 = __builtin_amdgcn_mfma_f32_16x16x32_bf16(a[0][kt], b, acc0, 0, 0, 0);
            acc1 = __builtin_amdgcn_mfma_f32_16x16x32_bf16(a[1][kt], b, acc1, 0, 0, 0);
        }
#pragma unroll
        for (int r = 0; r < 4; ++r) {
            const int row0 = m0 + kgrp * 4 + r;
            const int row1 = m0 + 16 + kgrp * 4 + r;
            if (row0 < nNodes) out[(size_t)row0 * OUT_F + n0 + lrow] = acc0[r];
            if (row1 < nNodes) out[(size_t)row1 * OUT_F + n0 + lrow] = acc1[r];
        }
    }
}

extern "C" void kernel_launch(void* const* d_in, const int* in_sizes, int n_in,
                              void* d_out, int out_size, void* d_ws, size_t ws_size,
                              hipStream_t stream)
{
    const float* x   = (const float*)d_in[0];
    const int*   ei  = (const int*)d_in[1];
    const float* W   = (const float*)d_in[3];
    const float* b   = (const float*)d_in[4];
    float*       out = (float*)d_out;

    const int nNodes = in_sizes[0] / IN_F;   // 50000
    const int nEdges = in_sizes[1] / 2;      // 800000
    const int nsb = (nNodes + 255) / 256;    // 196 scan blocks

    // ws layout (ints): deg_i[n] off[n] cursor[n] escan[n] bsum[nsb] bbase[nsb]
    //                   perm[E] | hbf[n*128 bf16] wbf[16384 bf16]
    int* deg_i  = (int*)d_ws;
    int* off    = deg_i + nNodes;
    int* cursor = off + nNodes;
    int* escan  = cursor + nNodes;
    int* bsum   = escan + nNodes;
    int* bbase  = bsum + nsb;
    int* perm   = bbase + nsb;
    ushort16* hbf = (ushort16*)(perm + nEdges);
    ushort16* wbf = hbf + (size_t)nNodes * IN_F;

    // x_bf16 lives in d_out's first 12.8MB: dead before k_mm writes out.
    uint32* xb = (uint32*)d_out;

    (void)hipMemsetAsync(deg_i, 0, (size_t)nNodes * sizeof(int), stream);

    const int nx4 = (nNodes * IN_F) / 4;
    const int nw4 = (OUT_F * IN_F) / 4;
    k_cvt<<<(nx4 + nw4 + 255) / 256, 256, 0, stream>>>(x, W, xb, (uint32*)wbf,
                                                       nx4, nw4);

    const int eb = (nEdges + 255) / 256;
    k_hist<<<eb, 256, 0, stream>>>(ei, deg_i, nEdges);

    k_scan_a<<<nsb, 256, 0, stream>>>(deg_i, escan, bsum, nNodes);
    k_scan_b<<<1, 256, 0, stream>>>(bsum, bbase, nsb);
    k_scan_c<<<nsb, 256, 0, stream>>>(escan, bbase, off, cursor, nNodes);

    // 8-way XCD-class filtered scatter: grid = 8 x chunks of 1024 edges.
    const int chunks = (nEdges + 1023) / 1024;
    k_scatter_ids<<<chunks * 8, 256, 0, stream>>>(ei, cursor, perm, nEdges);

    const int gb = (nNodes + 3) / 4;
    k_gather<<<gb, 256, 0, stream>>>(xb, perm, off, deg_i, (uint32*)hbf, nNodes);

    const int mb = (nNodes + 127) / 128;   // 391 blocks
    k_mm<<<mb, 256, 0, stream>>>(hbf, wbf, b, out, nNodes);
}

// Round 10
// 141.681 us; speedup vs baseline: 7.4365x; 1.0530x over previous
//
#include <hip/hip_runtime.h>

#define IN_F 128
#define OUT_F 128

typedef unsigned int uint32;
typedef unsigned short ushort16;
using short8 = __attribute__((ext_vector_type(8))) short;   // 8 bf16 (4 VGPR)
using f32x4  = __attribute__((ext_vector_type(4))) float;   // MFMA acc

// f32 -> bf16 (round-to-nearest-even), raw u16 in low bits.
__device__ __forceinline__ uint32 f2bf(float f) {
    const uint32 u = __float_as_uint(f);
    return (u + 0x7FFFu + ((u >> 16) & 1u)) >> 16;
}
__device__ __forceinline__ uint32 pack_bf2(float lo, float hi) {
    return f2bf(lo) | (f2bf(hi) << 16);
}

// ---------------------------------------------------------------------------
// 0) Prep: zero deg_i, convert x and W to bf16 — one kernel, no memset.
// ---------------------------------------------------------------------------
__global__ __launch_bounds__(256) void k_prep(
    const float* __restrict__ x, const float* __restrict__ W,
    uint32* __restrict__ xb, uint32* __restrict__ wb,
    int* __restrict__ deg_i, int nx4, int nw4, int nNodes)
{
    const int i4 = blockIdx.x * 256 + threadIdx.x;
    if (i4 < nNodes) deg_i[i4] = 0;
    if (i4 < nx4) {
        const float4 v = reinterpret_cast<const float4*>(x)[i4];
        uint2 st;
        st.x = pack_bf2(v.x, v.y);
        st.y = pack_bf2(v.z, v.w);
        reinterpret_cast<uint2*>(xb)[i4] = st;
    } else if (i4 - nx4 < nw4) {
        const int j4 = i4 - nx4;
        const float4 v = reinterpret_cast<const float4*>(W)[j4];
        uint2 st;
        st.x = pack_bf2(v.x, v.y);
        st.y = pack_bf2(v.z, v.w);
        reinterpret_cast<uint2*>(wb)[j4] = st;
    }
}

// ---------------------------------------------------------------------------
// 1) Per-node in-degree histogram (int atomics over 200KB -> cache-resident).
// ---------------------------------------------------------------------------
__global__ __launch_bounds__(256) void k_hist(
    const int* __restrict__ ei, int* __restrict__ deg_i, int nEdges)
{
    int e = blockIdx.x * blockDim.x + threadIdx.x;
    if (e < nEdges) {
        atomicAdd(&deg_i[ei[nEdges + e]], 1);
    }
}

// ---------------------------------------------------------------------------
// 2a) Per-256-chunk exclusive scan of deg_i -> escan, chunk sums -> bsum.
// ---------------------------------------------------------------------------
__global__ __launch_bounds__(256) void k_scan_a(
    const int* __restrict__ deg_i, int* __restrict__ escan,
    int* __restrict__ bsum, int n)
{
    __shared__ int sh[256];
    const int t = threadIdx.x;
    const int i = blockIdx.x * 256 + t;
    int v = (i < n) ? deg_i[i] : 0;
    sh[t] = v;
    __syncthreads();
    for (int ofs = 1; ofs < 256; ofs <<= 1) {
        int u = (t >= ofs) ? sh[t - ofs] : 0;
        __syncthreads();
        sh[t] += u;
        __syncthreads();
    }
    if (i < n) escan[i] = sh[t] - v;            // exclusive
    if (t == 255) bsum[blockIdx.x] = sh[255];
}

// ---------------------------------------------------------------------------
// 2b) Finalize: each block redundantly scans the (<=256) chunk sums in LDS
//     to get its own prefix, then off[i] = cursor[i] = escan[i] + prefix.
//     (bsum is ~784B -> L2 broadcast; redundant scan is ~µs total.)
// ---------------------------------------------------------------------------
__global__ __launch_bounds__(256) void k_scan_c(
    const int* __restrict__ escan, const int* __restrict__ bsum,
    int* __restrict__ off, int* __restrict__ cursor, int n, int nsb)
{
    __shared__ int sh[256];
    const int t = threadIdx.x;
    const int b = blockIdx.x;

    sh[t] = (t < nsb) ? bsum[t] : 0;
    __syncthreads();
    for (int ofs = 1; ofs < 256; ofs <<= 1) {
        int u = (t >= ofs) ? sh[t - ofs] : 0;
        __syncthreads();
        sh[t] += u;
        __syncthreads();
    }
    const int prefix = (b == 0) ? 0 : sh[b - 1];

    const int i = b * 256 + t;
    if (i < n) {
        const int o = escan[i] + prefix;
        off[i] = o;
        cursor[i] = o;
    }
}

// ---------------------------------------------------------------------------
// 3) CSR bucketing with XCD-class filtering to kill write amplification.
//    Grid = 8 x chunks. Block handles chunk blockIdx>>3, but only edges whose
//    destination class ((dst>>7)&7) == blockIdx&7. blockIdx%8 maps
//    round-robin to XCDs -> each perm region is written by ONE XCD ->
//    lines fill completely before eviction (WRITE ~= payload).
// ---------------------------------------------------------------------------
__global__ __launch_bounds__(256) void k_scatter_ids(
    const int* __restrict__ ei, int* __restrict__ cursor,
    int* __restrict__ perm, int nEdges)
{
    const int cls = blockIdx.x & 7;
    const int e0 = ((blockIdx.x >> 3) * 256 + threadIdx.x) * 4;
    if (e0 >= nEdges) return;

    if (e0 + 4 <= nEdges) {
        const int4 dst4 = *reinterpret_cast<const int4*>(ei + nEdges + e0);
        const int4 src4 = *reinterpret_cast<const int4*>(ei + e0);
        if (((dst4.x >> 7) & 7) == cls) {
            const int p = atomicAdd(&cursor[dst4.x], 1);
            perm[p] = src4.x;
        }
        if (((dst4.y >> 7) & 7) == cls) {
            const int p = atomicAdd(&cursor[dst4.y], 1);
            perm[p] = src4.y;
        }
        if (((dst4.z >> 7) & 7) == cls) {
            const int p = atomicAdd(&cursor[dst4.z], 1);
            perm[p] = src4.z;
        }
        if (((dst4.w >> 7) & 7) == cls) {
            const int p = atomicAdd(&cursor[dst4.w], 1);
            perm[p] = src4.w;
        }
    } else {
        for (int e = e0; e < nEdges; ++e) {
            const int dst = ei[nEdges + e];
            if (((dst >> 7) & 7) == cls) {
                const int p = atomicAdd(&cursor[dst], 1);
                perm[p] = ei[e];
            }
        }
    }
}

// ---------------------------------------------------------------------------
// 4) Gather-side reduction over bf16 x: one wave per node, lane holds 2
//    features (bf16x2 dword). f32 accumulation, bf16 output row.
// ---------------------------------------------------------------------------
__global__ __launch_bounds__(256) void k_gather(
    const uint32* __restrict__ xb2,    // [N][64] bf16x2
    const int* __restrict__ perm,
    const int* __restrict__ off,
    const int* __restrict__ deg_i,
    uint32* __restrict__ hb2,          // [N][64] bf16x2
    int nNodes)
{
    const int node = (blockIdx.x << 2) + (threadIdx.x >> 6);
    const int lane = threadIdx.x & 63;
    if (node >= nNodes) return;

    const int s = off[node];
    const int d = deg_i[node];

    float ax = 0.0f, ay = 0.0f;
    int i = 0;
    for (; i + 4 <= d; i += 4) {
        const uint32 u0 = xb2[(size_t)perm[s + i + 0] * 64 + lane];
        const uint32 u1 = xb2[(size_t)perm[s + i + 1] * 64 + lane];
        const uint32 u2 = xb2[(size_t)perm[s + i + 2] * 64 + lane];
        const uint32 u3 = xb2[(size_t)perm[s + i + 3] * 64 + lane];
        ax += __uint_as_float(u0 << 16);
        ay += __uint_as_float(u0 & 0xFFFF0000u);
        ax += __uint_as_float(u1 << 16);
        ay += __uint_as_float(u1 & 0xFFFF0000u);
        ax += __uint_as_float(u2 << 16);
        ay += __uint_as_float(u2 & 0xFFFF0000u);
        ax += __uint_as_float(u3 << 16);
        ay += __uint_as_float(u3 & 0xFFFF0000u);
    }
    for (; i < d; ++i) {
        const uint32 u = xb2[(size_t)perm[s + i] * 64 + lane];
        ax += __uint_as_float(u << 16);
        ay += __uint_as_float(u & 0xFFFF0000u);
    }

    const float inv = 1.0f / (float)(d > 0 ? d : 1);
    hb2[(size_t)node * 64 + lane] = pack_bf2(ax * inv, ay * inv);
}

// ---------------------------------------------------------------------------
// 5) out = h @ W.T + b via mfma_f32_16x16x32_bf16 (m89-verified C/D layout).
// ---------------------------------------------------------------------------
__global__ __launch_bounds__(256) void k_mm(
    const ushort16* __restrict__ hbf,   // [M][128] bf16
    const ushort16* __restrict__ wbf,   // [128][128] bf16 (row=out_f, col=in_f)
    const float* __restrict__ bias,
    float* __restrict__ out, int nNodes)
{
    const int wave = threadIdx.x >> 6;
    const int lane = threadIdx.x & 63;
    const int m0 = blockIdx.x * 128 + wave * 32;   // 32 rows per wave
    const int lrow = lane & 15;
    const int kgrp = lane >> 4;

    short8 a[2][4];
#pragma unroll
    for (int mt = 0; mt < 2; ++mt) {
        int mrow = m0 + mt * 16 + lrow;
        if (mrow >= nNodes) mrow = nNodes - 1;          // clamp (tail safety)
        const ushort16* hrow = hbf + (size_t)mrow * IN_F;
#pragma unroll
        for (int kt = 0; kt < 4; ++kt) {
            a[mt][kt] = *reinterpret_cast<const short8*>(hrow + kt * 32 + kgrp * 8);
        }
    }

#pragma unroll
    for (int nt = 0; nt < 8; ++nt) {
        const int n0 = nt * 16;
        const ushort16* wrow = wbf + (size_t)(n0 + lrow) * IN_F;
        const float bv = bias[n0 + lrow];

        f32x4 acc0 = {bv, bv, bv, bv};
        f32x4 acc1 = {bv, bv, bv, bv};
#pragma unroll
        for (int kt = 0; kt < 4; ++kt) {
            const short8 b = *reinterpret_cast<const short8*>(wrow + kt * 32 + kgrp * 8);
            acc0 = __builtin_amdgcn_mfma_f32_16x16x32_bf16(a[0][kt], b, acc0, 0, 0, 0);
            acc1 = __builtin_amdgcn_mfma_f32_16x16x32_bf16(a[1][kt], b, acc1, 0, 0, 0);
        }
#pragma unroll
        for (int r = 0; r < 4; ++r) {
            const int row0 = m0 + kgrp * 4 + r;
            const int row1 = m0 + 16 + kgrp * 4 + r;
            if (row0 < nNodes) out[(size_t)row0 * OUT_F + n0 + lrow] = acc0[r];
            if (row1 < nNodes) out[(size_t)row1 * OUT_F + n0 + lrow] = acc1[r];
        }
    }
}

extern "C" void kernel_launch(void* const* d_in, const int* in_sizes, int n_in,
                              void* d_out, int out_size, void* d_ws, size_t ws_size,
                              hipStream_t stream)
{
    const float* x   = (const float*)d_in[0];
    const int*   ei  = (const int*)d_in[1];
    const float* W   = (const float*)d_in[3];
    const float* b   = (const float*)d_in[4];
    float*       out = (float*)d_out;

    const int nNodes = in_sizes[0] / IN_F;   // 50000
    const int nEdges = in_sizes[1] / 2;      // 800000
    const int nsb = (nNodes + 255) / 256;    // 196 scan chunks

    // ws layout (ints): deg_i[n] off[n] cursor[n] escan[n] bsum[nsb]
    //                   perm[E] | hbf[n*128 bf16] wbf[16384 bf16]
    int* deg_i  = (int*)d_ws;
    int* off    = deg_i + nNodes;
    int* cursor = off + nNodes;
    int* escan  = cursor + nNodes;
    int* bsum   = escan + nNodes;
    int* perm   = bsum + nsb;
    ushort16* hbf = (ushort16*)(perm + nEdges);
    ushort16* wbf = hbf + (size_t)nNodes * IN_F;

    // x_bf16 lives in d_out's first 12.8MB: dead before k_mm writes out.
    uint32* xb = (uint32*)d_out;

    const int nx4 = (nNodes * IN_F) / 4;
    const int nw4 = (OUT_F * IN_F) / 4;
    k_prep<<<(nx4 + nw4 + 255) / 256, 256, 0, stream>>>(
        x, W, xb, (uint32*)wbf, deg_i, nx4, nw4, nNodes);

    const int eb = (nEdges + 255) / 256;
    k_hist<<<eb, 256, 0, stream>>>(ei, deg_i, nEdges);

    k_scan_a<<<nsb, 256, 0, stream>>>(deg_i, escan, bsum, nNodes);
    k_scan_c<<<nsb, 256, 0, stream>>>(escan, bsum, off, cursor, nNodes, nsb);

    // 8-way XCD-class filtered scatter: grid = 8 x chunks of 1024 edges.
    const int chunks = (nEdges + 1023) / 1024;
    k_scatter_ids<<<chunks * 8, 256, 0, stream>>>(ei, cursor, perm, nEdges);

    const int gb = (nNodes + 3) / 4;
    k_gather<<<gb, 256, 0, stream>>>(xb, perm, off, deg_i, (uint32*)hbf, nNodes);

    const int mb = (nNodes + 127) / 128;   // 391 blocks
    k_mm<<<mb, 256, 0, stream>>>(hbf, wbf, b, out, nNodes);
}